// Round 27
// baseline (25.174 us; speedup 1.0000x reference)
//
#include <hip/hip_runtime.h>
#include <cstddef>

#define NUM_TYPE 64
#define DD 256
#define NN 8192

typedef __bf16 bf16x8 __attribute__((ext_vector_type(8)));
typedef __bf16 bf16x4 __attribute__((ext_vector_type(4)));
typedef float f32x4 __attribute__((ext_vector_type(4)));

__device__ __forceinline__ bf16x4 cvt4(float4 v) {
  bf16x4 h;
  h[0] = (__bf16)v.x; h[1] = (__bf16)v.y; h[2] = (__bf16)v.z; h[3] = (__bf16)v.w;
  return h;
}

__device__ __forceinline__ float tanh_fast(float x) {
  float xc = fminf(fmaxf(x, -15.f), 15.f);
  float e = __expf(2.f * xc);
  return (e - 1.f) / (e + 1.f);
}

// --- Kernel 1 (proven R22/R26): block 0 = perm/type_off; blocks 1..264 ---
__global__ __launch_bounds__(1024) void perm_conv(
    const int* __restrict__ bi,
    const float* __restrict__ desc,
    const float* __restrict__ W,
    int* __restrict__ type_off, int* __restrict__ perm,
    __bf16* __restrict__ descB, __bf16* __restrict__ Wb) {
  const int b = blockIdx.x;
  const int tid = threadIdx.x;
  if (b == 0) {
    __shared__ int wcnt[16][NUM_TYPE];
    __shared__ int wbase[16][NUM_TYPE];
    __shared__ int cnt[NUM_TYPE];
    __shared__ int tstart[NUM_TYPE];
    __shared__ int totals[1];
    const int w = tid >> 6;
    for (int i = tid; i < 16 * NUM_TYPE; i += 1024) ((int*)wcnt)[i] = 0;
    __syncthreads();
    int myv[8];
#pragma unroll
    for (int rnd = 0; rnd < 8; ++rnd) {
      int v = bi[rnd * 1024 + tid];
      myv[rnd] = v;
      atomicAdd(&wcnt[w][v], 1);
    }
    __syncthreads();
    if (tid < NUM_TYPE) {
      int s = 0;
#pragma unroll
      for (int ww = 0; ww < 16; ++ww) { wbase[ww][tid] = s; s += wcnt[ww][tid]; }
      cnt[tid] = s;
    }
    __syncthreads();
    if (tid == 0) {
      int s = 0;
      for (int t = 0; t < NUM_TYPE; ++t) { tstart[t] = s; s += cnt[t]; }
      totals[0] = s;
    }
    __syncthreads();
    if (tid < NUM_TYPE) {
      const int s0 = tstart[tid];
      type_off[tid] = s0;
#pragma unroll
      for (int ww = 0; ww < 16; ++ww) wbase[ww][tid] += s0;
    }
    if (tid == 0) type_off[NUM_TYPE] = totals[0];
    __syncthreads();
#pragma unroll
    for (int rnd = 0; rnd < 8; ++rnd) {
      int v = myv[rnd];
      int p = atomicAdd(&wbase[w][v], 1);
      perm[p] = rnd * 1024 + tid;
    }
  } else {
    const float4* srcD = reinterpret_cast<const float4*>(desc);
    const float4* srcW = reinterpret_cast<const float4*>(W);
#pragma unroll
    for (int it = 0; it < 2; ++it) {
      const int idx = (b - 1) * 2048 + it * 1024 + tid;
      if (idx < 524288)
        *reinterpret_cast<bf16x4*>(descB + (size_t)idx * 4) = cvt4(srcD[idx]);
      else
        *reinterpret_cast<bf16x4*>(Wb + (size_t)(idx - 524288) * 4) = cvt4(srcW[idx - 524288]);
    }
  }
}

// --- Kernel 2: resident-panel GEMM, double-buffered gl_lds A, counted ----
// 512 blocks: t=(d&7)+8*((d>>3)&7), cb=d>>6; 512 threads / 8 waves; 2/CU.
// At: 2 x [64][256] bf16 linear (gl_lds dest), source chunk-swizzled.
// Ll: [32][256] bf16 XOR-swizzled (ds_write side). W: per-wave registers.
// Main loop never drains vmcnt to 0: group j+2 issued, wait vmcnt(4).
__global__ __launch_bounds__(512, 2) void gemm_res32(
    const __bf16* __restrict__ descB,
    const float* __restrict__ layer1,
    const __bf16* __restrict__ Wb,
    const float* __restrict__ bias,
    const int* __restrict__ type_off,
    const int* __restrict__ perm,
    float* __restrict__ out) {
  extern __shared__ __bf16 lds[];
  __bf16* At0 = lds;                     // [64][256]
  __bf16* At1 = lds + 64 * DD;           // [64][256]
  __bf16* Ll  = lds + 128 * DD;          // [32][256] swizzled

  const int d = blockIdx.x;
  const int t = (d & 7) + 8 * ((d >> 3) & 7);
  const int cb = d >> 6;                 // 0..7
  const int off = type_off[t];
  const int limit = type_off[t + 1];
  const int cnt = limit - off;
  if (cnt <= 0) return;
  const int ngr = (cnt + 63) >> 6;

  const int tid = threadIdx.x;
  const int wid = tid >> 6;
  const int lane = tid & 63;
  const int l15 = lane & 15;
  const int lg = lane >> 4;
  const int wr = wid >> 1;               // 0..3: row 16-group
  const int wc = wid & 1;                // 0..1: col 16-group
  const int colg = cb * 32 + wc * 16 + l15;

  // ---- W fragments to registers (one-time; divergent but tiny) ----
  bf16x8 Wf[8];
#pragma unroll
  for (int kc = 0; kc < 8; ++kc)
    Wf[kc] = *reinterpret_cast<const bf16x8*>(Wb + (size_t)colg * DD + kc * 32 + lg * 8);
  const float bv = bias[colg];

  // ---- stage L panel (fp32->bf16) with XOR-chunk swizzle ----
  {
    const float* Lsrc = layer1 + ((size_t)t * DD + cb * 32) * DD;
#pragma unroll
    for (int it = 0; it < 4; ++it) {
      const int idx = it * 512 + tid;    // 32 rows x 64 f4-segs
      const int col = idx >> 6, s4 = idx & 63;
      const int chunk = (s4 >> 1) ^ (col & 7);
      *reinterpret_cast<bf16x4*>(Ll + col * DD + chunk * 8 + (s4 & 1) * 4) =
          cvt4(*reinterpret_cast<const float4*>(Lsrc + (size_t)col * DD + s4 * 4));
    }
  }

  // A-group issue into buffer bp: 4 gl_lds/wave covering rows wid*8..+7.
#define A_ISSUE(firstLocal, bp)                                               \
  {                                                                           \
    _Pragma("unroll")                                                         \
    for (int it = 0; it < 4; ++it) {                                          \
      const int r0 = wid * 8 + it * 2;                                        \
      const int row = r0 + (lane >> 5);                                       \
      int lr = (firstLocal) + row;                                            \
      if (lr >= cnt) lr = cnt - 1;                                            \
      const int pv = perm[off + lr];                                          \
      const int segg = (lane & 31) ^ (row & 7);                               \
      const __bf16* gsrc = descB + (size_t)pv * DD + segg * 8;                \
      __builtin_amdgcn_global_load_lds(                                       \
          (const __attribute__((address_space(1))) void*)gsrc,                \
          (__attribute__((address_space(3))) void*)((bp) + r0 * DD),          \
          16, 0, 0);                                                          \
    }                                                                         \
  }

  // ---- prologue: issue g0 (and g1) ----
  A_ISSUE(0, At0)
  if (ngr > 1) {
    A_ISSUE(64, At1)
    asm volatile("s_waitcnt vmcnt(4)" ::: "memory");   // g0 done, g1 in flight
  } else {
    asm volatile("s_waitcnt vmcnt(0)" ::: "memory");
  }
  __syncthreads();                       // Ll + At(g0) visible

  const int rowA = wr * 16 + l15;
  const int rsw = rowA & 7;
  const int lrow = wc * 16 + l15;
  const int lsw = lrow & 7;

  for (int j = 0; j < ngr; ++j) {
    const __bf16* Ab = (j & 1) ? At1 : At0;

    f32x4 accL = {0.f, 0.f, 0.f, 0.f};
    f32x4 accW = {0.f, 0.f, 0.f, 0.f};
#pragma unroll
    for (int kc = 0; kc < 8; ++kc) {
      const int ca = (kc * 4 + lg) ^ rsw;
      const int cl = (kc * 4 + lg) ^ lsw;
      bf16x8 af = *reinterpret_cast<const bf16x8*>(Ab + rowA * DD + ca * 8);
      bf16x8 bl = *reinterpret_cast<const bf16x8*>(Ll + lrow * DD + cl * 8);
      accL = __builtin_amdgcn_mfma_f32_16x16x32_bf16(af, bl, accL, 0, 0, 0);
      accW = __builtin_amdgcn_mfma_f32_16x16x32_bf16(af, Wf[kc], accW, 0, 0, 0);
    }

    // ---- epilogue group j ----
    const int olr = j * 64 + rowA;
    const int sOut = (olr < cnt) ? perm[off + olr] : -1;
#pragma unroll
    for (int i = 0; i < 4; ++i) {
      const int sv = __shfl(sOut, lg * 4 + i, 64);
      if (sv >= 0)
        __builtin_nontemporal_store(tanh_fast(accL[i]) + accW[i] + bv,
                                    out + (size_t)sv * DD + colg);
    }

    // ---- refill this buffer with group j+2; counted wait for j+1 ----
    if (j + 1 < ngr) {
      __syncthreads();                   // all reads of Ab done block-wide
      if (j + 2 < ngr) {
        __bf16* Anext = (j & 1) ? At1 : At0;
        A_ISSUE((j + 2) * 64, Anext)
        asm volatile("s_waitcnt vmcnt(4)" ::: "memory");  // j+1 done, j+2 flying
      } else {
        asm volatile("s_waitcnt vmcnt(0)" ::: "memory");  // j+1 done
      }
      __syncthreads();
    }
  }
#undef A_ISSUE
}

extern "C" void kernel_launch(void* const* d_in, const int* in_sizes, int n_in,
                              void* d_out, int out_size, void* d_ws, size_t ws_size,
                              hipStream_t stream) {
  const int* bi       = (const int*)d_in[0];
  const float* desc   = (const float*)d_in[1];
  const float* layer1 = (const float*)d_in[2];
  const float* W      = (const float*)d_in[3];
  const float* bias   = (const float*)d_in[4];
  float* out = (float*)d_out;

  char* ws = (char*)d_ws;
  int* type_off = (int*)(ws);                      // 65 ints   @ 0
  int* perm     = (int*)(ws + 8192);               // 8192 ints @ 8 KB
  __bf16* descB = (__bf16*)(ws + 65536);           // 4 MB
  __bf16* Wb    = (__bf16*)(ws + 65536 + 4194304); // 128 KB

  // LDS: At dbuf 65536 + Ll 16384 = 81920 B -> exactly 2 blocks/CU
  const int ldsBytes = 128 * DD * 2 + 32 * DD * 2;

  hipLaunchKernelGGL(perm_conv, dim3(265), dim3(1024), 0, stream,
                     bi, desc, W, type_off, perm, descB, Wb);
  hipLaunchKernelGGL(gemm_res32, dim3(512), dim3(512), ldsBytes, stream,
                     descB, layer1, Wb, bias, type_off, perm, out);
}

// Round 28
// 23.744 us; speedup vs baseline: 1.0602x; 1.0602x over previous
//
#include <hip/hip_runtime.h>
#include <cstddef>

#define NUM_TYPE 64
#define DD 256
#define NN 8192
#define PSTR 264      // padded LDS row stride for L/W panels (bf16)
#define PT 512        // ptile capacity (ints)

typedef __bf16 bf16x8 __attribute__((ext_vector_type(8)));
typedef __bf16 bf16x4 __attribute__((ext_vector_type(4)));
typedef float f32x4 __attribute__((ext_vector_type(4)));

__device__ __forceinline__ bf16x4 cvt4(float4 v) {
  bf16x4 h;
  h[0] = (__bf16)v.x; h[1] = (__bf16)v.y; h[2] = (__bf16)v.z; h[3] = (__bf16)v.w;
  return h;
}

__device__ __forceinline__ float tanh_fast(float x) {
  float xc = fminf(fmaxf(x, -15.f), 15.f);
  float e = __expf(2.f * xc);
  return (e - 1.f) / (e + 1.f);
}

// --- Kernel 1 (proven R22/R25): block 0 = perm/type_off; blocks 1..264 ---
__global__ __launch_bounds__(1024) void perm_conv(
    const int* __restrict__ bi,
    const float* __restrict__ desc,
    const float* __restrict__ W,
    int* __restrict__ type_off, int* __restrict__ perm,
    __bf16* __restrict__ descB, __bf16* __restrict__ Wb) {
  const int b = blockIdx.x;
  const int tid = threadIdx.x;
  if (b == 0) {
    __shared__ int wcnt[16][NUM_TYPE];
    __shared__ int wbase[16][NUM_TYPE];
    __shared__ int cnt[NUM_TYPE];
    __shared__ int tstart[NUM_TYPE];
    __shared__ int totals[1];
    const int w = tid >> 6;
    for (int i = tid; i < 16 * NUM_TYPE; i += 1024) ((int*)wcnt)[i] = 0;
    __syncthreads();
    int myv[8];
#pragma unroll
    for (int rnd = 0; rnd < 8; ++rnd) {
      int v = bi[rnd * 1024 + tid];
      myv[rnd] = v;
      atomicAdd(&wcnt[w][v], 1);
    }
    __syncthreads();
    if (tid < NUM_TYPE) {
      int s = 0;
#pragma unroll
      for (int ww = 0; ww < 16; ++ww) { wbase[ww][tid] = s; s += wcnt[ww][tid]; }
      cnt[tid] = s;
    }
    __syncthreads();
    if (tid == 0) {
      int s = 0;
      for (int t = 0; t < NUM_TYPE; ++t) { tstart[t] = s; s += cnt[t]; }
      totals[0] = s;
    }
    __syncthreads();
    if (tid < NUM_TYPE) {
      const int s0 = tstart[tid];
      type_off[tid] = s0;
#pragma unroll
      for (int ww = 0; ww < 16; ++ww) wbase[ww][tid] += s0;
    }
    if (tid == 0) type_off[NUM_TYPE] = totals[0];
    __syncthreads();
#pragma unroll
    for (int rnd = 0; rnd < 8; ++rnd) {
      int v = myv[rnd];
      int p = atomicAdd(&wbase[w][v], 1);
      perm[p] = rnd * 1024 + tid;
    }
  } else {
    const float4* srcD = reinterpret_cast<const float4*>(desc);
    const float4* srcW = reinterpret_cast<const float4*>(W);
#pragma unroll
    for (int it = 0; it < 2; ++it) {
      const int idx = (b - 1) * 2048 + it * 1024 + tid;
      if (idx < 524288)
        *reinterpret_cast<bf16x4*>(descB + (size_t)idx * 4) = cvt4(srcD[idx]);
      else
        *reinterpret_cast<bf16x4*>(Wb + (size_t)(idx - 524288) * 4) = cvt4(srcW[idx - 524288]);
    }
  }
}

// --- Kernel 2: resident-panel GEMM, A staged via global_load_lds ---------
// 512 blocks: t=(d&7)+8*((d>>3)&7), cb=d>>6; 512 threads / 8 waves; 2/CU.
// At is LINEAR [64][256] bf16 (gl_lds needs contiguous dest). Source is
// chunk-swizzled (seg ^= row&7) so ds_reads can apply the same XOR and stay
// bank-conflict-free (8 lanes per bank-group, uniform).
__global__ __launch_bounds__(512, 2) void gemm_res32(
    const __bf16* __restrict__ descB,
    const float* __restrict__ layer1,
    const __bf16* __restrict__ Wb,
    const float* __restrict__ bias,
    const int* __restrict__ type_off,
    const int* __restrict__ perm,
    float* __restrict__ out) {
  extern __shared__ __bf16 lds[];
  __bf16* At = lds;                      // [64][256] linear, swizzled chunks
  __bf16* Ll = lds + 64 * DD;            // [32][PSTR]
  __bf16* Wl = Ll + 32 * PSTR;           // [32][PSTR]
  int* ptile = (int*)(Wl + 32 * PSTR);   // [PT]

  const int d = blockIdx.x;
  const int t = (d & 7) + 8 * ((d >> 3) & 7);
  const int cb = d >> 6;                 // 0..7
  const int off = type_off[t];
  const int limit = type_off[t + 1];
  const int cnt = limit - off;
  if (cnt <= 0) return;
  const int ngr = (cnt + 63) >> 6;

  const int tid = threadIdx.x;
  const int wid = tid >> 6;
  const int lane = tid & 63;
  const int l15 = lane & 15;
  const int lg = lane >> 4;
  const int wr = wid >> 1;               // 0..3: row 16-group
  const int wc = wid & 1;                // 0..1: col 16-group

  // ---- preload perm slice into LDS ----
  for (int i = tid; i < cnt && i < PT; i += 512) ptile[i] = perm[off + i];

  // ---- stage L (fp32->bf16) and W (bf16) panels once ----
  {
    const float* Lsrc = layer1 + ((size_t)t * DD + cb * 32) * DD;
#pragma unroll
    for (int it = 0; it < 4; ++it) {
      const int idx = it * 512 + tid;    // 32 cols x 64 f4-segs
      const int col = idx >> 6, seg = idx & 63;
      *reinterpret_cast<bf16x4*>(Ll + col * PSTR + seg * 4) =
          cvt4(*reinterpret_cast<const float4*>(Lsrc + (size_t)col * DD + seg * 4));
    }
    const __bf16* Wsrc = Wb + (size_t)(cb * 32) * DD;
#pragma unroll
    for (int it = 0; it < 2; ++it) {
      const int idx = it * 512 + tid;    // 32 cols x 32 bf16x8
      const int col = idx >> 5, seg = idx & 31;
      *reinterpret_cast<bf16x8*>(Wl + col * PSTR + seg * 8) =
          *reinterpret_cast<const bf16x8*>(Wsrc + (size_t)col * DD + seg * 8);
    }
  }
  __syncthreads();                       // ptile + panels visible

  const int colg = cb * 32 + wc * 16 + l15;
  const float bv = bias[colg];

  // A-group issue: 4 gl_lds per wave; instr it covers rows r0=wid*8+it*2,+1.
  // Lane l: row = r0 + (l>>5); src chunk = (l&31) ^ (row&7)  [pre-swizzle].
#define A_ISSUE(firstLocal)                                                   \
  {                                                                           \
    _Pragma("unroll")                                                         \
    for (int it = 0; it < 4; ++it) {                                          \
      const int r0 = wid * 8 + it * 2;                                        \
      const int row = r0 + (lane >> 5);                                       \
      int lr = (firstLocal) + row;                                            \
      if (lr >= cnt) lr = cnt - 1;                                            \
      const int pv = (lr < PT) ? ptile[lr] : perm[off + lr];                  \
      const int segg = (lane & 31) ^ (row & 7);                               \
      const __bf16* gsrc = descB + (size_t)pv * DD + segg * 8;                \
      __builtin_amdgcn_global_load_lds(                                       \
          (const __attribute__((address_space(1))) void*)gsrc,                \
          (__attribute__((address_space(3))) void*)(At + r0 * DD),            \
          16, 0, 0);                                                          \
    }                                                                         \
  }

  // ---- prologue: group 0 ----
  A_ISSUE(0)
  asm volatile("s_waitcnt vmcnt(0)" ::: "memory");
  __syncthreads();

  for (int j = 0; j < ngr; ++j) {
    // ---- compute group j from LDS (swizzled At reads) ----
    const int rowA = wr * 16 + l15;
    const int rsw = rowA & 7;
    f32x4 accL = {0.f, 0.f, 0.f, 0.f};
    f32x4 accW = {0.f, 0.f, 0.f, 0.f};
#pragma unroll
    for (int kc = 0; kc < 8; ++kc) {
      const int c0 = (kc * 4 + lg) ^ rsw;
      bf16x8 af = *reinterpret_cast<const bf16x8*>(At + rowA * DD + c0 * 8);
      bf16x8 bl = *reinterpret_cast<const bf16x8*>(Ll + (wc * 16 + l15) * PSTR + kc * 32 + lg * 8);
      bf16x8 bw = *reinterpret_cast<const bf16x8*>(Wl + (wc * 16 + l15) * PSTR + kc * 32 + lg * 8);
      accL = __builtin_amdgcn_mfma_f32_16x16x32_bf16(af, bl, accL, 0, 0, 0);
      accW = __builtin_amdgcn_mfma_f32_16x16x32_bf16(af, bw, accW, 0, 0, 0);
    }

    // ---- epilogue group j (ptile addressing) ----
    const int olr = j * 64 + rowA;
    int sOut = -1;
    if (olr < cnt) sOut = (olr < PT) ? ptile[olr] : perm[off + olr];
#pragma unroll
    for (int i = 0; i < 4; ++i) {
      const int sv = __shfl(sOut, lg * 4 + i, 64);
      if (sv >= 0)
        __builtin_nontemporal_store(tanh_fast(accL[i]) + accW[i] + bv,
                                    out + (size_t)sv * DD + colg);
    }

    // ---- stage group j+1 ----
    if (j + 1 < ngr) {
      __syncthreads();                   // all ds_reads of At done
      A_ISSUE((j + 1) * 64)
      asm volatile("s_waitcnt vmcnt(0)" ::: "memory");
      __syncthreads();                   // At visible for next iter
    }
  }
#undef A_ISSUE
}

extern "C" void kernel_launch(void* const* d_in, const int* in_sizes, int n_in,
                              void* d_out, int out_size, void* d_ws, size_t ws_size,
                              hipStream_t stream) {
  const int* bi       = (const int*)d_in[0];
  const float* desc   = (const float*)d_in[1];
  const float* layer1 = (const float*)d_in[2];
  const float* W      = (const float*)d_in[3];
  const float* bias   = (const float*)d_in[4];
  float* out = (float*)d_out;

  char* ws = (char*)d_ws;
  int* type_off = (int*)(ws);                      // 65 ints   @ 0
  int* perm     = (int*)(ws + 8192);               // 8192 ints @ 8 KB
  __bf16* descB = (__bf16*)(ws + 65536);           // 4 MB
  __bf16* Wb    = (__bf16*)(ws + 65536 + 4194304); // 128 KB

  // LDS: At 32768 + panels 33792 + ptile 2048 = 68608 B -> 2 blocks/CU
  const int ldsBytes = 64 * DD * 2 + 2 * 32 * PSTR * 2 + PT * 4;

  hipLaunchKernelGGL(perm_conv, dim3(265), dim3(1024), 0, stream,
                     bi, desc, W, type_off, perm, descB, Wb);
  hipLaunchKernelGGL(gemm_res32, dim3(512), dim3(512), ldsBytes, stream,
                     descB, layer1, Wb, bias, type_off, perm, out);
}